// Round 1
// baseline (3887.305 us; speedup 1.0000x reference)
//
#include <hip/hip_runtime.h>
#include <hip/hip_bf16.h>
#include <math.h>

// Problem constants
constexpr int KB_ = 4;            // tree branching factor
constexpr int LEVELS_ = 9;
constexpr int N_NODES_ = 87381;   // (4^9-1)/3
constexpr int HS = 256;           // X_SIZE == H_SIZE == A_SIZE
constexpr int N_HEADS_ = 8;
constexpr int A_K_ = 32;

// ---------------------------------------------------------------------------
// Generic fp32 GEMM: C[M,N] = A[M,K] @ B[K,N] + bias (+ C if acc)
// BM=64, BN=64, BK=16, 256 threads, 4x4 micro-tile.
// ---------------------------------------------------------------------------
#define BM 64
#define BN 64
#define BKK 16

__global__ __launch_bounds__(256) void gemm_f32(
    const float* __restrict__ A, const float* __restrict__ B,
    const float* __restrict__ bias, float* __restrict__ C,
    int M, int N, int Kd, int acc)
{
    __shared__ float As[BKK][BM + 1];
    __shared__ float Bs[BKK][BN + 1];

    const int col0 = blockIdx.x * BN;
    const int row0 = blockIdx.y * BM;
    const int tid = threadIdx.x;
    const int tx = tid & 15;       // 16 col groups
    const int ty = tid >> 4;       // 16 row groups

    float accv[4][4];
    #pragma unroll
    for (int i = 0; i < 4; i++)
        #pragma unroll
        for (int j = 0; j < 4; j++) accv[i][j] = 0.f;

    for (int k0 = 0; k0 < Kd; k0 += BKK) {
        // Load A tile: 64 rows x 16 k  (1024 elems, 4 per thread)
        #pragma unroll
        for (int i = 0; i < 4; i++) {
            int idx = tid + i * 256;
            int r = idx >> 4;
            int kk = idx & 15;
            int gr = row0 + r;
            float v = 0.f;
            if (gr < M) v = A[(size_t)gr * Kd + k0 + kk];
            As[kk][r] = v;
        }
        // Load B tile: 16 k x 64 cols
        #pragma unroll
        for (int i = 0; i < 4; i++) {
            int idx = tid + i * 256;
            int kk = idx >> 6;
            int c = idx & 63;
            int gc = col0 + c;
            float v = 0.f;
            if (gc < N) v = B[(size_t)(k0 + kk) * N + gc];
            Bs[kk][c] = v;
        }
        __syncthreads();

        #pragma unroll
        for (int kk = 0; kk < BKK; kk++) {
            float a[4], b[4];
            #pragma unroll
            for (int i = 0; i < 4; i++) a[i] = As[kk][ty * 4 + i];
            #pragma unroll
            for (int j = 0; j < 4; j++) b[j] = Bs[kk][tx * 4 + j];
            #pragma unroll
            for (int i = 0; i < 4; i++)
                #pragma unroll
                for (int j = 0; j < 4; j++) accv[i][j] += a[i] * b[j];
        }
        __syncthreads();
    }

    #pragma unroll
    for (int i = 0; i < 4; i++) {
        int gr = row0 + ty * 4 + i;
        if (gr >= M) continue;
        #pragma unroll
        for (int j = 0; j < 4; j++) {
            int gc = col0 + tx * 4 + j;
            if (gc >= N) continue;
            float v = accv[i][j];
            if (bias) v += bias[gc];
            size_t off = (size_t)gr * N + gc;
            if (acc) v += C[off];
            C[off] = v;
        }
    }
}

// ---------------------------------------------------------------------------
// Attention: per (node, head), 32 lanes handle the 32-dim head.
// logits over 4 children, softmax, weighted V sum.
// ---------------------------------------------------------------------------
__global__ __launch_bounds__(256) void attn_kernel(
    const float* __restrict__ Q, const float* __restrict__ Kb,
    const float* __restrict__ Vb, float* __restrict__ Ob, int n)
{
    int t = blockIdx.x * 256 + threadIdx.x;
    int pair = t >> 5;
    int lane = t & 31;
    if (pair >= n * N_HEADS_) return;
    int node = pair >> 3;
    int head = pair & 7;
    const float scale = 0.17677669529663687f; // 1/sqrt(32)

    int qoff = node * HS + head * A_K_ + lane;
    float q = Q[qoff];

    float logit[KB_];
    #pragma unroll
    for (int c = 0; c < KB_; c++) {
        float p = q * Kb[(size_t)(KB_ * node + c) * HS + head * A_K_ + lane];
        #pragma unroll
        for (int off = 16; off >= 1; off >>= 1)
            p += __shfl_xor(p, off, 32);
        logit[c] = p * scale;
    }
    float m = fmaxf(fmaxf(logit[0], logit[1]), fmaxf(logit[2], logit[3]));
    float e[KB_], s = 0.f;
    #pragma unroll
    for (int c = 0; c < KB_; c++) { e[c] = expf(logit[c] - m); s += e[c]; }
    float inv = 1.f / s;
    float o = 0.f;
    #pragma unroll
    for (int c = 0; c < KB_; c++)
        o += (e[c] * inv) * Vb[(size_t)(KB_ * node + c) * HS + head * A_K_ + lane];
    Ob[qoff] = o;
}

// ---------------------------------------------------------------------------
// LSTM cell kernels
// ---------------------------------------------------------------------------
__device__ __forceinline__ float sigm(float x) { return 1.f / (1.f + expf(-x)); }

__global__ __launch_bounds__(256) void cell_internal(
    const float* __restrict__ xiou, const float* __restrict__ fb,
    const float* __restrict__ c_child,
    float* __restrict__ h_out, float* __restrict__ c_out, int n)
{
    int t = blockIdx.x * 256 + threadIdx.x;
    if (t >= n * HS) return;
    int node = t >> 8;
    int j = t & 255;
    float f = sigm(fb[t]);
    float fc = 0.f;
    #pragma unroll
    for (int c = 0; c < KB_; c++)
        fc += c_child[(size_t)(KB_ * node + c) * HS + j] * f;
    float iv = xiou[(size_t)node * 768 + j];
    float ov = xiou[(size_t)node * 768 + 256 + j];
    float uv = xiou[(size_t)node * 768 + 512 + j];
    float cn = sigm(iv) * tanhf(uv) + fc;
    float hn = sigm(ov) * tanhf(cn);
    h_out[t] = hn;
    c_out[t] = cn;
}

__global__ __launch_bounds__(256) void cell_leaf(
    const float* __restrict__ xiou,
    float* __restrict__ h_out, float* __restrict__ c_out, int n)
{
    int t = blockIdx.x * 256 + threadIdx.x;
    if (t >= n * HS) return;
    int node = t >> 8;
    int j = t & 255;
    float iv = xiou[(size_t)node * 768 + j];
    float ov = xiou[(size_t)node * 768 + 256 + j];
    float uv = xiou[(size_t)node * 768 + 512 + j];
    float cn = sigm(iv) * tanhf(uv);
    float hn = sigm(ov) * tanhf(cn);
    h_out[t] = hn;
    c_out[t] = cn;
}

// ---------------------------------------------------------------------------
// Host-side launch
// ---------------------------------------------------------------------------
static inline void launch_gemm(const float* A, const float* B, const float* bias,
                               float* C, int M, int N, int Kd, int acc,
                               hipStream_t stream)
{
    dim3 grid((N + BN - 1) / BN, (M + BM - 1) / BM);
    gemm_f32<<<grid, 256, 0, stream>>>(A, B, bias, C, M, N, Kd, acc);
}

extern "C" void kernel_launch(void* const* d_in, const int* in_sizes, int n_in,
                              void* d_out, int out_size, void* d_ws, size_t ws_size,
                              hipStream_t stream)
{
    const float* x      = (const float*)d_in[0];
    const float* W_iou  = (const float*)d_in[1];
    const float* b_iou  = (const float*)d_in[2];
    const float* W_f    = (const float*)d_in[3];
    const float* b_f    = (const float*)d_in[4];
    const float* Wq     = (const float*)d_in[5];
    const float* bq     = (const float*)d_in[6];
    const float* Wk     = (const float*)d_in[7];
    const float* bk     = (const float*)d_in[8];
    const float* Wv     = (const float*)d_in[9];
    const float* bv     = (const float*)d_in[10];
    const float* Wl     = (const float*)d_in[11];
    const float* bl     = (const float*)d_in[12];
    const float* Uiou_w = (const float*)d_in[13];
    const float* Uiou_b = (const float*)d_in[14];
    const float* Uf_w   = (const float*)d_in[15];
    const float* Uf_b   = (const float*)d_in[16];

    float* h_all = (float*)d_out;
    float* c_all = h_all + (size_t)N_NODES_ * HS;

    // Workspace layout (floats): ~252 MB total
    float* ws    = (float*)d_ws;
    float* xioub = ws;                              // 16384*768
    float* fbuf  = xioub + (size_t)16384 * 768;     // 16384*256
    float* qbuf  = fbuf  + (size_t)16384 * 256;     // 16384*256
    float* Kbuf  = qbuf  + (size_t)16384 * 256;     // 65536*256
    float* Vbuf  = Kbuf  + (size_t)65536 * 256;     // 65536*256
    float* outb  = Vbuf  + (size_t)65536 * 256;     // 16384*256
    float* habuf = outb  + (size_t)16384 * 256;     // 16384*256

    static const int starts[LEVELS_] = {0, 1, 5, 21, 85, 341, 1365, 5461, 21845};

    // ---- Leaves (level 8): 65536 nodes in 4 chunks of 16384 ----
    for (int ch = 0; ch < 4; ch++) {
        int r0 = starts[8] + ch * 16384;
        launch_gemm(x + (size_t)r0 * HS, W_iou, b_iou, xioub, 16384, 768, 256, 0, stream);
        int total = 16384 * HS;
        cell_leaf<<<(total + 255) / 256, 256, 0, stream>>>(
            xioub, h_all + (size_t)r0 * HS, c_all + (size_t)r0 * HS, 16384);
    }

    // ---- Internal levels 7..0 ----
    for (int l = 7; l >= 0; l--) {
        int n  = 1 << (2 * l);
        int s0 = starts[l];
        int sc = starts[l + 1];
        int nc = KB_ * n;

        const float* h_ch = h_all + (size_t)sc * HS;
        const float* c_ch = c_all + (size_t)sc * HS;

        launch_gemm(h_ch, Wk, bk, Kbuf, nc, 256, 256, 0, stream);
        launch_gemm(h_ch, Wv, bv, Vbuf, nc, 256, 256, 0, stream);
        launch_gemm(x + (size_t)s0 * HS, Wq, bq, qbuf, n, 256, 256, 0, stream);

        int pairs = n * N_HEADS_;
        attn_kernel<<<(pairs * 32 + 255) / 256, 256, 0, stream>>>(qbuf, Kbuf, Vbuf, outb, n);

        launch_gemm(outb, Wl, bl, habuf, n, 256, 256, 0, stream);

        launch_gemm(x + (size_t)s0 * HS, W_iou, b_iou, xioub, n, 768, 256, 0, stream);
        launch_gemm(habuf, Uiou_w, Uiou_b, xioub, n, 768, 256, 1, stream);

        launch_gemm(x + (size_t)s0 * HS, W_f, b_f, fbuf, n, 256, 256, 0, stream);
        launch_gemm(habuf, Uf_w, Uf_b, fbuf, n, 256, 256, 1, stream);

        int total = n * HS;
        cell_internal<<<(total + 255) / 256, 256, 0, stream>>>(
            xioub, fbuf, c_ch,
            h_all + (size_t)s0 * HS, c_all + (size_t)s0 * HS, n);
    }
}

// Round 2
// 1110.557 us; speedup vs baseline: 3.5003x; 3.5003x over previous
//
#include <hip/hip_runtime.h>
#include <hip/hip_bf16.h>
#include <math.h>

constexpr int KB_ = 4;
constexpr int LEVELS_ = 9;
constexpr int N_NODES_ = 87381;
constexpr int HS = 256;
constexpr int N_HEADS_ = 8;
constexpr int A_K_ = 32;

typedef __attribute__((ext_vector_type(8))) short bf16x8;
typedef __attribute__((ext_vector_type(4))) float f32x4;
typedef __attribute__((ext_vector_type(4))) short short4v;
typedef __attribute__((ext_vector_type(4))) float float4v;

__device__ __forceinline__ short f2bf(float f) {
    union { float f; unsigned u; } a; a.f = f;
    unsigned r = (a.u + 0x7fff + ((a.u >> 16) & 1)) >> 16;
    return (short)r;
}
__device__ __forceinline__ float bf2f(short s) {
    union { unsigned u; float f; } a; a.u = ((unsigned)(unsigned short)s) << 16;
    return a.f;
}
__device__ __forceinline__ float sigm(float x) { return 1.f / (1.f + expf(-x)); }

// ---------------------------------------------------------------------------
// bf16 MFMA GEMM: C[M,N] = A1[M,K1] @ B1t[N,K1]^T (+ A2[M,K2] @ B2t[N,K2]^T)
//                 + bias.  Bt is stored transposed: Bt[n][k].
// 128x128 tile, BK=32, 256 threads = 4 waves (2x2 of 64x64), 4x4 MFMA/wave.
// N must be a multiple of 128; K multiples of 32; A rows 16B-aligned (K%8==0).
// out_bf16: write bf16 (short) else fp32.
// ---------------------------------------------------------------------------
__global__ __launch_bounds__(256) void gemm_bf16_mfma(
    const short* __restrict__ A1, const short* __restrict__ B1t, int K1,
    const short* __restrict__ A2, const short* __restrict__ B2t, int K2,
    const float* __restrict__ bias, void* __restrict__ Cout,
    int M, int N, int out_bf16)
{
    __shared__ short As[128 * 40];
    __shared__ short Bs[128 * 40];

    const int tid = threadIdx.x;
    const int row0 = blockIdx.y * 128;
    const int col0 = blockIdx.x * 128;
    const int lane = tid & 63;
    const int w = tid >> 6;
    const int wm = (w >> 1) * 64;
    const int wn = (w & 1) * 64;
    const int q = lane >> 4;
    const int mr = lane & 15;

    f32x4 acc[4][4];
    #pragma unroll
    for (int i = 0; i < 4; i++)
        #pragma unroll
        for (int j = 0; j < 4; j++) acc[i][j] = (f32x4){0.f, 0.f, 0.f, 0.f};

    #pragma unroll 1
    for (int pass = 0; pass < 2; ++pass) {
        const short* A = pass ? A2 : A1;
        const short* Bt = pass ? B2t : B1t;
        const int Kd = pass ? K2 : K1;
        if (A == nullptr) break;

        for (int k0 = 0; k0 < Kd; k0 += 32) {
            __syncthreads();
            // stage A and Bt tiles: 128 rows x 32 shorts each; 2 chunks/thread
            #pragma unroll
            for (int i = 0; i < 2; ++i) {
                int chunk = tid * 2 + i;          // 0..511
                int r = chunk >> 2;
                int c8 = (chunk & 3) * 8;
                int gr = row0 + r;
                bf16x8 va = {};
                if (gr < M) va = *(const bf16x8*)(A + (size_t)gr * Kd + k0 + c8);
                *(bf16x8*)(As + r * 40 + c8) = va;
                int gc = col0 + r;                // N multiple of 128: in range
                bf16x8 vb = *(const bf16x8*)(Bt + (size_t)gc * Kd + k0 + c8);
                *(bf16x8*)(Bs + r * 40 + c8) = vb;
            }
            __syncthreads();

            bf16x8 af[4], bfr[4];
            #pragma unroll
            for (int i = 0; i < 4; ++i)
                af[i] = *(const bf16x8*)(As + (wm + i * 16 + mr) * 40 + q * 8);
            #pragma unroll
            for (int j = 0; j < 4; ++j)
                bfr[j] = *(const bf16x8*)(Bs + (wn + j * 16 + mr) * 40 + q * 8);

            #pragma unroll
            for (int i = 0; i < 4; ++i)
                #pragma unroll
                for (int j = 0; j < 4; ++j)
                    acc[i][j] = __builtin_amdgcn_mfma_f32_16x16x32_bf16(
                        af[i], bfr[j], acc[i][j], 0, 0, 0);
        }
    }

    // epilogue: C/D layout col=lane&15, row=(lane>>4)*4+reg
    #pragma unroll
    for (int j = 0; j < 4; ++j) {
        int col = col0 + wn + j * 16 + mr;
        float bv = bias ? bias[col] : 0.f;
        #pragma unroll
        for (int i = 0; i < 4; ++i) {
            #pragma unroll
            for (int r = 0; r < 4; ++r) {
                int grow = row0 + wm + i * 16 + q * 4 + r;
                if (grow < M) {
                    float v = acc[i][j][r] + bv;
                    if (out_bf16)
                        ((short*)Cout)[(size_t)grow * N + col] = f2bf(v);
                    else
                        ((float*)Cout)[(size_t)grow * N + col] = v;
                }
            }
        }
    }
}

// ---------------------------------------------------------------------------
// Attention: per (node,head), 32 lanes = 32-dim head. bf16 in/out, fp32 math.
// KV rows: [4n][512], cols 0..255 = K proj, 256..511 = V proj.
// ---------------------------------------------------------------------------
__global__ __launch_bounds__(256) void attn_kernel(
    const short* __restrict__ Q, const short* __restrict__ KV,
    short* __restrict__ Ob, int n)
{
    int t = blockIdx.x * 256 + threadIdx.x;
    int pair = t >> 5;
    int lane = t & 31;
    if (pair >= n * N_HEADS_) return;
    int node = pair >> 3;
    int head = pair & 7;
    const float scale = 0.17677669529663687f; // 1/sqrt(32)

    int qoff = node * HS + head * A_K_ + lane;
    float qv = bf2f(Q[qoff]);

    float logit[KB_];
    #pragma unroll
    for (int c = 0; c < KB_; c++) {
        float p = qv * bf2f(KV[(size_t)(KB_ * node + c) * 512 + head * A_K_ + lane]);
        #pragma unroll
        for (int off = 16; off >= 1; off >>= 1)
            p += __shfl_xor(p, off, 32);
        logit[c] = p * scale;
    }
    float m = fmaxf(fmaxf(logit[0], logit[1]), fmaxf(logit[2], logit[3]));
    float e[KB_], s = 0.f;
    #pragma unroll
    for (int c = 0; c < KB_; c++) { e[c] = expf(logit[c] - m); s += e[c]; }
    float inv = 1.f / s;
    float o = 0.f;
    #pragma unroll
    for (int c = 0; c < KB_; c++)
        o += (e[c] * inv) * bf2f(KV[(size_t)(KB_ * node + c) * 512 + 256 + head * A_K_ + lane]);
    Ob[qoff] = f2bf(o);
}

// ---------------------------------------------------------------------------
// Cell kernels. iouf layout internal: [n][1024] = i|o|u|f_pre. Leaf: [n][768].
// ---------------------------------------------------------------------------
__global__ __launch_bounds__(256) void cell_internal(
    const float* __restrict__ iouf, const float* __restrict__ c_child,
    float* __restrict__ h_out, float* __restrict__ c_out,
    short* __restrict__ hb_out, int n)
{
    int t = blockIdx.x * 256 + threadIdx.x;
    if (t >= n * HS) return;
    int node = t >> 8;
    int j = t & 255;
    size_t base = (size_t)node * 1024;
    float iv = iouf[base + j];
    float ov = iouf[base + 256 + j];
    float uv = iouf[base + 512 + j];
    float fv = sigm(iouf[base + 768 + j]);
    float fc = 0.f;
    #pragma unroll
    for (int c = 0; c < KB_; c++)
        fc += c_child[(size_t)(KB_ * node + c) * HS + j] * fv;
    float cn = sigm(iv) * tanhf(uv) + fc;
    float hn = sigm(ov) * tanhf(cn);
    h_out[t] = hn;
    c_out[t] = cn;
    hb_out[t] = f2bf(hn);
}

__global__ __launch_bounds__(256) void cell_leaf(
    const float* __restrict__ iou,
    float* __restrict__ h_out, float* __restrict__ c_out,
    short* __restrict__ hb_out, int n)
{
    int t = blockIdx.x * 256 + threadIdx.x;
    if (t >= n * HS) return;
    int node = t >> 8;
    int j = t & 255;
    size_t base = (size_t)node * 768;
    float iv = iou[base + j];
    float ov = iou[base + 256 + j];
    float uv = iou[base + 512 + j];
    float cn = sigm(iv) * tanhf(uv);
    float hn = sigm(ov) * tanhf(cn);
    h_out[t] = hn;
    c_out[t] = cn;
    hb_out[t] = f2bf(hn);
}

// ---------------------------------------------------------------------------
// Prep: x -> bf16 (vectorized 4/thread)
// ---------------------------------------------------------------------------
__global__ __launch_bounds__(256) void conv_x(
    const float* __restrict__ x, short* __restrict__ xb, int n4)
{
    int t = blockIdx.x * 256 + threadIdx.x;
    if (t >= n4) return;
    float4v v = *(const float4v*)(x + (size_t)t * 4);
    short4v o;
    o.x = f2bf(v.x); o.y = f2bf(v.y); o.z = f2bf(v.z); o.w = f2bf(v.w);
    *(short4v*)(xb + (size_t)t * 4) = o;
}

// ---------------------------------------------------------------------------
// Prep: transposed bf16 weights + fused biases
// Bt1[1024][256] = [W_iou | W_f]^T ; Bt2[1024][256] = [Uiou_w | Uf_w]^T
// B3t[512][256]  = [Wk | Wv]^T ; Wqt/Wlt [256][256]
// biasC[1024] = [b_iou+Uiou_b | b_f+Uf_b] ; bias_kv[512] = [bk | bv]
// ---------------------------------------------------------------------------
__global__ __launch_bounds__(256) void prep_weights(
    const float* __restrict__ W_iou, const float* __restrict__ W_f,
    const float* __restrict__ Uiou_w, const float* __restrict__ Uf_w,
    const float* __restrict__ Wk, const float* __restrict__ Wv,
    const float* __restrict__ Wq, const float* __restrict__ Wl,
    const float* __restrict__ b_iou, const float* __restrict__ b_f,
    const float* __restrict__ Uiou_b, const float* __restrict__ Uf_b,
    const float* __restrict__ bk, const float* __restrict__ bv,
    short* __restrict__ Bt1, short* __restrict__ Bt2, short* __restrict__ B3t,
    short* __restrict__ Wqt, short* __restrict__ Wlt,
    float* __restrict__ biasC, float* __restrict__ bias_kv)
{
    int t = blockIdx.x * 256 + threadIdx.x;
    if (t < 262144) {
        int n = t >> 8, k = t & 255;
        float v = (n < 768) ? W_iou[k * 768 + n] : W_f[k * 256 + (n - 768)];
        Bt1[t] = f2bf(v);
        return;
    }
    t -= 262144;
    if (t < 262144) {
        int n = t >> 8, k = t & 255;
        float v = (n < 768) ? Uiou_w[k * 768 + n] : Uf_w[k * 256 + (n - 768)];
        Bt2[t] = f2bf(v);
        return;
    }
    t -= 262144;
    if (t < 131072) {
        int n = t >> 8, k = t & 255;
        float v = (n < 256) ? Wk[k * 256 + n] : Wv[k * 256 + (n - 256)];
        B3t[t] = f2bf(v);
        return;
    }
    t -= 131072;
    if (t < 65536) {
        int n = t >> 8, k = t & 255;
        Wqt[t] = f2bf(Wq[k * 256 + n]);
        return;
    }
    t -= 65536;
    if (t < 65536) {
        int n = t >> 8, k = t & 255;
        Wlt[t] = f2bf(Wl[k * 256 + n]);
        return;
    }
    t -= 65536;
    if (t < 1024) {
        biasC[t] = (t < 768) ? (b_iou[t] + Uiou_b[t]) : (b_f[t - 768] + Uf_b[t - 768]);
        return;
    }
    t -= 1024;
    if (t < 512) {
        bias_kv[t] = (t < 256) ? bk[t] : bv[t - 256];
        return;
    }
}

// ---------------------------------------------------------------------------
static inline void launch_gemm(const short* A1, const short* B1t, int K1,
                               const short* A2, const short* B2t, int K2,
                               const float* bias, void* C, int M, int N,
                               int out_bf16, hipStream_t stream)
{
    dim3 grid(N / 128, (M + 127) / 128);
    gemm_bf16_mfma<<<grid, 256, 0, stream>>>(A1, B1t, K1, A2, B2t, K2,
                                             bias, C, M, N, out_bf16);
}

extern "C" void kernel_launch(void* const* d_in, const int* in_sizes, int n_in,
                              void* d_out, int out_size, void* d_ws, size_t ws_size,
                              hipStream_t stream)
{
    const float* x      = (const float*)d_in[0];
    const float* W_iou  = (const float*)d_in[1];
    const float* b_iou  = (const float*)d_in[2];
    const float* W_f    = (const float*)d_in[3];
    const float* b_f    = (const float*)d_in[4];
    const float* Wq     = (const float*)d_in[5];
    const float* bq     = (const float*)d_in[6];
    const float* Wk     = (const float*)d_in[7];
    const float* bk     = (const float*)d_in[8];
    const float* Wv     = (const float*)d_in[9];
    const float* bv     = (const float*)d_in[10];
    const float* Wl     = (const float*)d_in[11];
    const float* bl     = (const float*)d_in[12];
    const float* Uiou_w = (const float*)d_in[13];
    const float* Uiou_b = (const float*)d_in[14];
    const float* Uf_w   = (const float*)d_in[15];
    const float* Uf_b   = (const float*)d_in[16];

    float* h_all = (float*)d_out;
    float* c_all = h_all + (size_t)N_NODES_ * HS;

    // Workspace layout (bytes), total ~250.4 MB
    char* p = (char*)d_ws;
    short* xb    = (short*)p; p += (size_t)N_NODES_ * 256 * 2;   // 44.7 MB
    short* hb    = (short*)p; p += (size_t)N_NODES_ * 256 * 2;   // 44.7 MB
    short* KVb   = (short*)p; p += (size_t)65536 * 512 * 2;      // 67.1 MB
    short* qb    = (short*)p; p += (size_t)16384 * 256 * 2;      // 8.4 MB
    short* outb  = (short*)p; p += (size_t)16384 * 256 * 2;      // 8.4 MB
    short* hab   = (short*)p; p += (size_t)16384 * 256 * 2;      // 8.4 MB
    float* ioufb = (float*)p; p += (size_t)16384 * 1024 * 4;     // 67.1 MB
    short* Bt1   = (short*)p; p += (size_t)1024 * 256 * 2;
    short* Bt2   = (short*)p; p += (size_t)1024 * 256 * 2;
    short* B3t   = (short*)p; p += (size_t)512 * 256 * 2;
    short* Wqt   = (short*)p; p += (size_t)256 * 256 * 2;
    short* Wlt   = (short*)p; p += (size_t)256 * 256 * 2;
    float* biasC = (float*)p; p += 1024 * 4;
    float* bias_kv = (float*)p; p += 512 * 4;

    static const int starts[LEVELS_] = {0, 1, 5, 21, 85, 341, 1365, 5461, 21845};

    // ---- prep ----
    {
        int n4 = N_NODES_ * 256 / 4;
        conv_x<<<(n4 + 255) / 256, 256, 0, stream>>>(x, xb, n4);
        int total = 262144 + 262144 + 131072 + 65536 + 65536 + 1024 + 512;
        prep_weights<<<(total + 255) / 256, 256, 0, stream>>>(
            W_iou, W_f, Uiou_w, Uf_w, Wk, Wv, Wq, Wl,
            b_iou, b_f, Uiou_b, Uf_b, bk, bv,
            Bt1, Bt2, B3t, Wqt, Wlt, biasC, bias_kv);
    }

    // ---- Leaves (level 8): 65536 nodes, 4 chunks of 16384 ----
    for (int ch = 0; ch < 4; ch++) {
        int r0 = starts[8] + ch * 16384;
        // iou = x @ W_iou + b_iou  (Bt1 rows 0..767 are W_iou^T)
        launch_gemm(xb + (size_t)r0 * 256, Bt1, 256, nullptr, nullptr, 0,
                    b_iou, ioufb, 16384, 768, 0, stream);
        int total = 16384 * HS;
        cell_leaf<<<(total + 255) / 256, 256, 0, stream>>>(
            ioufb, h_all + (size_t)r0 * HS, c_all + (size_t)r0 * HS,
            hb + (size_t)r0 * HS, 16384);
    }

    // ---- Internal levels 7..0 ----
    for (int l = 7; l >= 0; l--) {
        int n  = 1 << (2 * l);
        int s0 = starts[l];
        int sc = starts[l + 1];
        int nc = KB_ * n;

        const short* h_ch = hb + (size_t)sc * HS;
        const float* c_ch = c_all + (size_t)sc * HS;

        // KV = h_ch @ [Wk|Wv] + [bk|bv]  -> bf16 [nc][512]
        launch_gemm(h_ch, B3t, 256, nullptr, nullptr, 0,
                    bias_kv, KVb, nc, 512, 1, stream);
        // q = x @ Wq + bq -> bf16 [n][256]
        launch_gemm(xb + (size_t)s0 * 256, Wqt, 256, nullptr, nullptr, 0,
                    bq, qb, n, 256, 1, stream);

        int pairs = n * N_HEADS_;
        attn_kernel<<<(pairs * 32 + 255) / 256, 256, 0, stream>>>(qb, KVb, outb, n);

        // ha = out @ Wl + bl -> bf16 [n][256]
        launch_gemm(outb, Wlt, 256, nullptr, nullptr, 0,
                    bl, hab, n, 256, 1, stream);

        // iouf = x@[W_iou|W_f] + ha@[Uiou|Uf] + biasC -> fp32 [n][1024]
        launch_gemm(xb + (size_t)s0 * 256, Bt1, 256, hab, Bt2, 256,
                    biasC, ioufb, n, 1024, 0, stream);

        int total = n * HS;
        cell_internal<<<(total + 255) / 256, 256, 0, stream>>>(
            ioufb, c_ch, h_all + (size_t)s0 * HS, c_all + (size_t)s0 * HS,
            hb + (size_t)s0 * HS, n);
    }
}

// Round 3
// 1086.409 us; speedup vs baseline: 3.5781x; 1.0222x over previous
//
#include <hip/hip_runtime.h>
#include <hip/hip_bf16.h>
#include <math.h>

constexpr int LEVELS_ = 9;
constexpr int N_NODES_ = 87381;
constexpr int HS = 256;
constexpr int N_HEADS_ = 8;

typedef __attribute__((ext_vector_type(8))) short bf16x8;
typedef __attribute__((ext_vector_type(4))) float f32x4;
typedef __attribute__((ext_vector_type(4))) short short4v;
typedef __attribute__((ext_vector_type(4))) float float4v;

__device__ __forceinline__ short f2bf(float f) {
    union { float f; unsigned u; } a; a.f = f;
    unsigned r = (a.u + 0x7fff + ((a.u >> 16) & 1)) >> 16;
    return (short)r;
}
__device__ __forceinline__ float bf2f(short s) {
    union { unsigned u; float f; } a; a.u = ((unsigned)(unsigned short)s) << 16;
    return a.f;
}
__device__ __forceinline__ float sigm(float x) { return 1.f / (1.f + expf(-x)); }

// ---------------------------------------------------------------------------
// bf16 MFMA GEMM: C[M,N] = A[M,K] @ Bt[N,K]^T + bias (+ Cadd bf16)
// 128x128 tile, BK=64, reg-prefetch double buffer. N%128==0, K%64==0.
// ---------------------------------------------------------------------------
__global__ __launch_bounds__(256) void gemm_bf16(
    const short* __restrict__ A, const short* __restrict__ Bt,
    const float* __restrict__ bias, const short* __restrict__ Cadd,
    void* __restrict__ Cout, int M, int N, int Kd, int out_bf16)
{
    __shared__ short As[128 * 72];
    __shared__ short Bs[128 * 72];

    const int tid = threadIdx.x;
    const int row0 = blockIdx.y * 128;
    const int col0 = blockIdx.x * 128;
    const int lane = tid & 63;
    const int w = tid >> 6;
    const int wm = (w >> 1) * 64;
    const int wn = (w & 1) * 64;
    const int q = lane >> 4;
    const int mr = lane & 15;

    f32x4 acc[4][4];
    #pragma unroll
    for (int i = 0; i < 4; i++)
        #pragma unroll
        for (int j = 0; j < 4; j++) acc[i][j] = (f32x4){0.f, 0.f, 0.f, 0.f};

    bf16x8 pa[4], pb[4];
    // prefetch k0 = 0
    #pragma unroll
    for (int i = 0; i < 4; ++i) {
        int chunk = i * 256 + tid;
        int r = chunk >> 3;
        int c8 = (chunk & 7) * 8;
        int gr = row0 + r;
        bf16x8 va = {};
        if (gr < M) va = *(const bf16x8*)(A + (size_t)gr * Kd + c8);
        pa[i] = va;
        pb[i] = *(const bf16x8*)(Bt + (size_t)(col0 + r) * Kd + c8);
    }

    for (int k0 = 0; k0 < Kd; k0 += 64) {
        __syncthreads();
        #pragma unroll
        for (int i = 0; i < 4; ++i) {
            int chunk = i * 256 + tid;
            int r = chunk >> 3;
            int c8 = (chunk & 7) * 8;
            *(bf16x8*)(As + r * 72 + c8) = pa[i];
            *(bf16x8*)(Bs + r * 72 + c8) = pb[i];
        }
        __syncthreads();
        if (k0 + 64 < Kd) {
            int kn = k0 + 64;
            #pragma unroll
            for (int i = 0; i < 4; ++i) {
                int chunk = i * 256 + tid;
                int r = chunk >> 3;
                int c8 = (chunk & 7) * 8;
                int gr = row0 + r;
                bf16x8 va = {};
                if (gr < M) va = *(const bf16x8*)(A + (size_t)gr * Kd + kn + c8);
                pa[i] = va;
                pb[i] = *(const bf16x8*)(Bt + (size_t)(col0 + r) * Kd + kn + c8);
            }
        }
        #pragma unroll
        for (int h = 0; h < 2; ++h) {
            bf16x8 af[4], bfr[4];
            #pragma unroll
            for (int i = 0; i < 4; ++i)
                af[i] = *(const bf16x8*)(As + (wm + i * 16 + mr) * 72 + h * 32 + q * 8);
            #pragma unroll
            for (int j = 0; j < 4; ++j)
                bfr[j] = *(const bf16x8*)(Bs + (wn + j * 16 + mr) * 72 + h * 32 + q * 8);
            #pragma unroll
            for (int i = 0; i < 4; ++i)
                #pragma unroll
                for (int j = 0; j < 4; ++j)
                    acc[i][j] = __builtin_amdgcn_mfma_f32_16x16x32_bf16(
                        af[i], bfr[j], acc[i][j], 0, 0, 0);
        }
    }

    #pragma unroll
    for (int j = 0; j < 4; ++j) {
        int col = col0 + wn + j * 16 + mr;
        float bv = bias ? bias[col] : 0.f;
        #pragma unroll
        for (int i = 0; i < 4; ++i) {
            #pragma unroll
            for (int r = 0; r < 4; ++r) {
                int grow = row0 + wm + i * 16 + q * 4 + r;
                if (grow < M) {
                    size_t off = (size_t)grow * N + col;
                    float v = acc[i][j][r] + bv;
                    if (Cadd) v += bf2f(Cadd[off]);
                    if (out_bf16) ((short*)Cout)[off] = f2bf(v);
                    else ((float*)Cout)[off] = v;
                }
            }
        }
    }
}

// ---------------------------------------------------------------------------
// Dedicated attention (levels 7,6): per (node,head), 32 lanes.
// ---------------------------------------------------------------------------
__global__ __launch_bounds__(256) void attn_kernel(
    const short* __restrict__ Q, const short* __restrict__ KV,
    short* __restrict__ Ob, int n)
{
    int t = blockIdx.x * 256 + threadIdx.x;
    int pair = t >> 5;
    int lane = t & 31;
    if (pair >= n * N_HEADS_) return;
    int node = pair >> 3;
    int head = pair & 7;
    const float scale = 0.17677669529663687f;

    int qoff = node * HS + head * 32 + lane;
    float qv = bf2f(Q[qoff]);

    float logit[4];
    #pragma unroll
    for (int c = 0; c < 4; c++) {
        float p = qv * bf2f(KV[(size_t)(4 * node + c) * 512 + head * 32 + lane]);
        #pragma unroll
        for (int off = 16; off >= 1; off >>= 1)
            p += __shfl_xor(p, off, 32);
        logit[c] = p * scale;
    }
    float m = fmaxf(fmaxf(logit[0], logit[1]), fmaxf(logit[2], logit[3]));
    float e[4], s = 0.f;
    #pragma unroll
    for (int c = 0; c < 4; c++) { e[c] = expf(logit[c] - m); s += e[c]; }
    float inv = 1.f / s;
    float o = 0.f;
    #pragma unroll
    for (int c = 0; c < 4; c++)
        o += (e[c] * inv) * bf2f(KV[(size_t)(4 * node + c) * 512 + 256 + head * 32 + lane]);
    Ob[qoff] = f2bf(o);
}

// ---------------------------------------------------------------------------
// Cell kernels (bf16 preacts)
// ---------------------------------------------------------------------------
__global__ __launch_bounds__(256) void cell_internal(
    const short* __restrict__ iouf, const float* __restrict__ c_child,
    float* __restrict__ h_out, float* __restrict__ c_out,
    short* __restrict__ hb_out, int n)
{
    int t = blockIdx.x * 256 + threadIdx.x;
    if (t >= n * HS) return;
    int node = t >> 8;
    int j = t & 255;
    size_t base = (size_t)node * 1024;
    float iv = bf2f(iouf[base + j]);
    float ov = bf2f(iouf[base + 256 + j]);
    float uv = bf2f(iouf[base + 512 + j]);
    float fv = sigm(bf2f(iouf[base + 768 + j]));
    float fc = 0.f;
    #pragma unroll
    for (int c = 0; c < 4; c++)
        fc += c_child[(size_t)(4 * node + c) * HS + j] * fv;
    float cn = sigm(iv) * tanhf(uv) + fc;
    float hn = sigm(ov) * tanhf(cn);
    h_out[t] = hn;
    c_out[t] = cn;
    hb_out[t] = f2bf(hn);
}

__global__ __launch_bounds__(256) void cell_leaf(
    const short* __restrict__ iou,
    float* __restrict__ h_out, float* __restrict__ c_out,
    short* __restrict__ hb_out, int n)
{
    int t = blockIdx.x * 256 + threadIdx.x;
    if (t >= n * HS) return;
    int node = t >> 8;
    int j = t & 255;
    size_t base = (size_t)node * 768;
    float iv = bf2f(iou[base + j]);
    float ov = bf2f(iou[base + 256 + j]);
    float uv = bf2f(iou[base + 512 + j]);
    float cn = sigm(iv) * tanhf(uv);
    float hn = sigm(ov) * tanhf(cn);
    h_out[t] = hn;
    c_out[t] = cn;
    hb_out[t] = f2bf(hn);
}

// ---------------------------------------------------------------------------
// Fused level kernel for n <= 1024: each block handles 8 parent nodes.
// KV proj -> attention -> Wl proj -> U proj (+x preact) -> cell, all in LDS.
// ---------------------------------------------------------------------------
__global__ __launch_bounds__(256) void level_fused(
    const short* __restrict__ hb, const float* __restrict__ c_all,
    const short* __restrict__ qb, const short* __restrict__ xi,
    const short* __restrict__ B3t, const short* __restrict__ Wlt,
    const short* __restrict__ Bt2,
    const float* __restrict__ bias_kv, const float* __restrict__ bl,
    const float* __restrict__ biasU,
    float* __restrict__ h_all, float* __restrict__ c_out_g,
    short* __restrict__ hb_out, int s0, int sc, int n)
{
    __shared__ __align__(16) char smem[50176];
    short* sh_h    = (short*)smem;             // 32 x 264
    short* sh_kv   = (short*)(smem + 16896);   // 32 x 520
    short* sh_out  = (short*)smem;             // 16 x 264 (reuse sh_h)
    short* sh_ha   = (short*)(smem + 8448);    // 16 x 264
    float* sh_iouf = (float*)(smem + 16896);   // 8 x 1024 (reuse sh_kv)

    const int tid = threadIdx.x;
    const int lane = tid & 63;
    const int w = tid >> 6;
    const int q = lane >> 4;
    const int mr = lane & 15;
    const int p0 = blockIdx.x * 8;
    const int np = (n - p0 < 8) ? (n - p0) : 8;
    const int nch = 4 * np;

    // phase 0: stage children h
    #pragma unroll
    for (int i = 0; i < 4; ++i) {
        int chunk = i * 256 + tid;      // 0..1023
        int r = chunk >> 5;             // 0..31
        int c8 = (chunk & 31) * 8;
        bf16x8 v = {};
        if (r < nch) v = *(const bf16x8*)(hb + (size_t)(sc + 4 * p0 + r) * 256 + c8);
        *(bf16x8*)(sh_h + r * 264 + c8) = v;
    }
    __syncthreads();

    // phase 1: KV[32x512] = sh_h @ B3t^T + bias_kv
    {
        f32x4 acc[2][8];
        #pragma unroll
        for (int rt = 0; rt < 2; ++rt)
            #pragma unroll
            for (int ct = 0; ct < 8; ++ct) acc[rt][ct] = (f32x4){0.f, 0.f, 0.f, 0.f};
        #pragma unroll 1
        for (int k0 = 0; k0 < 256; k0 += 32) {
            bf16x8 a0 = *(const bf16x8*)(sh_h + mr * 264 + k0 + q * 8);
            bf16x8 a1 = *(const bf16x8*)(sh_h + (16 + mr) * 264 + k0 + q * 8);
            #pragma unroll
            for (int ct = 0; ct < 8; ++ct) {
                int col = w * 128 + ct * 16 + mr;
                bf16x8 b = *(const bf16x8*)(B3t + (size_t)col * 256 + k0 + q * 8);
                acc[0][ct] = __builtin_amdgcn_mfma_f32_16x16x32_bf16(a0, b, acc[0][ct], 0, 0, 0);
                acc[1][ct] = __builtin_amdgcn_mfma_f32_16x16x32_bf16(a1, b, acc[1][ct], 0, 0, 0);
            }
        }
        #pragma unroll
        for (int ct = 0; ct < 8; ++ct) {
            int col = w * 128 + ct * 16 + mr;
            float bv = bias_kv[col];
            #pragma unroll
            for (int rt = 0; rt < 2; ++rt)
                #pragma unroll
                for (int r = 0; r < 4; ++r) {
                    int row = rt * 16 + q * 4 + r;
                    sh_kv[row * 520 + col] = f2bf(acc[rt][ct][r] + bv);
                }
        }
    }
    __syncthreads();

    // phase 2: attention -> sh_out rows 0..np-1
    {
        const int grp0 = tid >> 5;
        const int l32 = tid & 31;
        #pragma unroll 1
        for (int it = 0; it < 8; ++it) {
            int grp = it * 8 + grp0;
            int node = grp >> 3, head = grp & 7;
            if (node < np) {
                float qv = bf2f(qb[(size_t)(s0 + p0 + node) * 256 + head * 32 + l32]);
                float logit[4];
                #pragma unroll
                for (int c = 0; c < 4; ++c) {
                    float p = qv * bf2f(sh_kv[(4 * node + c) * 520 + head * 32 + l32]);
                    #pragma unroll
                    for (int off = 16; off >= 1; off >>= 1)
                        p += __shfl_xor(p, off, 32);
                    logit[c] = p * 0.17677669529663687f;
                }
                float mx = fmaxf(fmaxf(logit[0], logit[1]), fmaxf(logit[2], logit[3]));
                float e[4], s = 0.f;
                #pragma unroll
                for (int c = 0; c < 4; ++c) { e[c] = expf(logit[c] - mx); s += e[c]; }
                float inv = 1.f / s;
                float o = 0.f;
                #pragma unroll
                for (int c = 0; c < 4; ++c)
                    o += (e[c] * inv) * bf2f(sh_kv[(4 * node + c) * 520 + 256 + head * 32 + l32]);
                sh_out[node * 264 + head * 32 + l32] = f2bf(o);
            }
        }
    }
    __syncthreads();

    // phase 3: ha[<=8 x 256] = sh_out @ Wlt^T + bl
    {
        f32x4 acc[4];
        #pragma unroll
        for (int ct = 0; ct < 4; ++ct) acc[ct] = (f32x4){0.f, 0.f, 0.f, 0.f};
        #pragma unroll 1
        for (int k0 = 0; k0 < 256; k0 += 32) {
            bf16x8 a = *(const bf16x8*)(sh_out + mr * 264 + k0 + q * 8);
            #pragma unroll
            for (int ct = 0; ct < 4; ++ct) {
                int col = w * 64 + ct * 16 + mr;
                bf16x8 b = *(const bf16x8*)(Wlt + (size_t)col * 256 + k0 + q * 8);
                acc[ct] = __builtin_amdgcn_mfma_f32_16x16x32_bf16(a, b, acc[ct], 0, 0, 0);
            }
        }
        #pragma unroll
        for (int ct = 0; ct < 4; ++ct) {
            int col = w * 64 + ct * 16 + mr;
            float bv = bl[col];
            #pragma unroll
            for (int r = 0; r < 4; ++r) {
                int row = q * 4 + r;
                if (row < np) sh_ha[row * 264 + col] = f2bf(acc[ct][r] + bv);
            }
        }
    }
    __syncthreads();

    // phase 4: iouf[<=8 x 1024] = sh_ha @ Bt2^T + biasU + xi
    {
        f32x4 acc[16];
        #pragma unroll
        for (int ct = 0; ct < 16; ++ct) acc[ct] = (f32x4){0.f, 0.f, 0.f, 0.f};
        #pragma unroll 1
        for (int k0 = 0; k0 < 256; k0 += 32) {
            bf16x8 a = *(const bf16x8*)(sh_ha + mr * 264 + k0 + q * 8);
            #pragma unroll
            for (int ct = 0; ct < 16; ++ct) {
                int col = w * 256 + ct * 16 + mr;
                bf16x8 b = *(const bf16x8*)(Bt2 + (size_t)col * 256 + k0 + q * 8);
                acc[ct] = __builtin_amdgcn_mfma_f32_16x16x32_bf16(a, b, acc[ct], 0, 0, 0);
            }
        }
        __syncthreads();  // sh_iouf overlaps sh_kv (done); sh_ha reads complete
        #pragma unroll
        for (int ct = 0; ct < 16; ++ct) {
            int col = w * 256 + ct * 16 + mr;
            float bU = biasU[col];
            #pragma unroll
            for (int r = 0; r < 4; ++r) {
                int row = q * 4 + r;
                if (row < np)
                    sh_iouf[row * 1024 + col] =
                        acc[ct][r] + bU + bf2f(xi[(size_t)(s0 + p0 + row) * 1024 + col]);
            }
        }
    }
    __syncthreads();

    // phase 5: cell
    #pragma unroll 1
    for (int it = 0; it < 8; ++it) {
        int t = it * 256 + tid;
        if (t < np * 256) {
            int node = t >> 8, j = t & 255;
            float iv = sh_iouf[node * 1024 + j];
            float ov = sh_iouf[node * 1024 + 256 + j];
            float uv = sh_iouf[node * 1024 + 512 + j];
            float fv = sigm(sh_iouf[node * 1024 + 768 + j]);
            float fc = 0.f;
            #pragma unroll
            for (int c = 0; c < 4; ++c)
                fc += c_all[(size_t)(sc + 4 * (p0 + node) + c) * 256 + j] * fv;
            float cn = sigm(iv) * tanhf(uv) + fc;
            float hn = sigm(ov) * tanhf(cn);
            size_t o = (size_t)(s0 + p0 + node) * 256 + j;
            h_all[o] = hn;
            c_out_g[o] = cn;
            hb_out[o] = f2bf(hn);
        }
    }
}

// ---------------------------------------------------------------------------
// Prep kernels
// ---------------------------------------------------------------------------
__global__ __launch_bounds__(256) void conv_x(
    const float* __restrict__ x, short* __restrict__ xb, int n4)
{
    int t = blockIdx.x * 256 + threadIdx.x;
    if (t >= n4) return;
    float4v v = *(const float4v*)(x + (size_t)t * 4);
    short4v o;
    o.x = f2bf(v.x); o.y = f2bf(v.y); o.z = f2bf(v.z); o.w = f2bf(v.w);
    *(short4v*)(xb + (size_t)t * 4) = o;
}

__global__ __launch_bounds__(256) void prep_weights(
    const float* __restrict__ W_iou, const float* __restrict__ W_f,
    const float* __restrict__ Uiou_w, const float* __restrict__ Uf_w,
    const float* __restrict__ Wk, const float* __restrict__ Wv,
    const float* __restrict__ Wq, const float* __restrict__ Wl,
    const float* __restrict__ b_iou, const float* __restrict__ b_f,
    const float* __restrict__ Uiou_b, const float* __restrict__ Uf_b,
    const float* __restrict__ bk, const float* __restrict__ bv,
    short* __restrict__ Bt1, short* __restrict__ Bt2, short* __restrict__ B3t,
    short* __restrict__ Wqt, short* __restrict__ Wlt,
    float* __restrict__ biasX, float* __restrict__ biasU,
    float* __restrict__ bias_kv)
{
    int t = blockIdx.x * 256 + threadIdx.x;
    if (t < 262144) {
        int nn = t >> 8, k = t & 255;
        float v = (nn < 768) ? W_iou[k * 768 + nn] : W_f[k * 256 + (nn - 768)];
        Bt1[t] = f2bf(v);
        return;
    }
    t -= 262144;
    if (t < 262144) {
        int nn = t >> 8, k = t & 255;
        float v = (nn < 768) ? Uiou_w[k * 768 + nn] : Uf_w[k * 256 + (nn - 768)];
        Bt2[t] = f2bf(v);
        return;
    }
    t -= 262144;
    if (t < 131072) {
        int nn = t >> 8, k = t & 255;
        float v = (nn < 256) ? Wk[k * 256 + nn] : Wv[k * 256 + (nn - 256)];
        B3t[t] = f2bf(v);
        return;
    }
    t -= 131072;
    if (t < 65536) { int nn = t >> 8, k = t & 255; Wqt[t] = f2bf(Wq[k * 256 + nn]); return; }
    t -= 65536;
    if (t < 65536) { int nn = t >> 8, k = t & 255; Wlt[t] = f2bf(Wl[k * 256 + nn]); return; }
    t -= 65536;
    if (t < 1024) { biasX[t] = (t < 768) ? b_iou[t] : b_f[t - 768]; return; }
    t -= 1024;
    if (t < 1024) { biasU[t] = (t < 768) ? Uiou_b[t] : Uf_b[t - 768]; return; }
    t -= 1024;
    if (t < 512) { bias_kv[t] = (t < 256) ? bk[t] : bv[t - 256]; return; }
}

// ---------------------------------------------------------------------------
static inline void launch_gemm(const short* A, const short* Bt, const float* bias,
                               const short* Cadd, void* C, int M, int N, int Kd,
                               int out_bf16, hipStream_t stream)
{
    dim3 grid(N / 128, (M + 127) / 128);
    gemm_bf16<<<grid, 256, 0, stream>>>(A, Bt, bias, Cadd, C, M, N, Kd, out_bf16);
}

extern "C" void kernel_launch(void* const* d_in, const int* in_sizes, int n_in,
                              void* d_out, int out_size, void* d_ws, size_t ws_size,
                              hipStream_t stream)
{
    const float* x      = (const float*)d_in[0];
    const float* W_iou  = (const float*)d_in[1];
    const float* b_iou  = (const float*)d_in[2];
    const float* W_f    = (const float*)d_in[3];
    const float* b_f    = (const float*)d_in[4];
    const float* Wq     = (const float*)d_in[5];
    const float* bq     = (const float*)d_in[6];
    const float* Wk     = (const float*)d_in[7];
    const float* bk     = (const float*)d_in[8];
    const float* Wv     = (const float*)d_in[9];
    const float* bv     = (const float*)d_in[10];
    const float* Wl     = (const float*)d_in[11];
    const float* bl     = (const float*)d_in[12];
    const float* Uiou_w = (const float*)d_in[13];
    const float* Uiou_b = (const float*)d_in[14];
    const float* Uf_w   = (const float*)d_in[15];
    const float* Uf_b   = (const float*)d_in[16];

    float* h_all = (float*)d_out;
    float* c_all = h_all + (size_t)N_NODES_ * HS;

    char* p = (char*)d_ws;
    short* xb   = (short*)p; p += (size_t)N_NODES_ * 256 * 2;   // all-node x bf16
    short* hb   = (short*)p; p += (size_t)N_NODES_ * 256 * 2;   // all-node h bf16
    short* xl   = (short*)p; p += (size_t)65536 * 768 * 2;      // leaf x-preacts
    short* xi   = (short*)p; p += (size_t)21845 * 1024 * 2;     // internal x-preacts
    short* qb   = (short*)p; p += (size_t)21845 * 256 * 2;      // all internal q
    short* KVb  = (short*)p; p += (size_t)65536 * 512 * 2;
    short* outb = (short*)p; p += (size_t)16384 * 256 * 2;
    short* hab  = (short*)p; p += (size_t)16384 * 256 * 2;
    short* ioufb= (short*)p; p += (size_t)16384 * 1024 * 2;
    short* Bt1  = (short*)p; p += (size_t)1024 * 256 * 2;
    short* Bt2  = (short*)p; p += (size_t)1024 * 256 * 2;
    short* B3t  = (short*)p; p += (size_t)512 * 256 * 2;
    short* Wqt  = (short*)p; p += (size_t)256 * 256 * 2;
    short* Wlt  = (short*)p; p += (size_t)256 * 256 * 2;
    float* biasX   = (float*)p; p += 1024 * 4;
    float* biasU   = (float*)p; p += 1024 * 4;
    float* bias_kv = (float*)p; p += 512 * 4;

    static const int starts[LEVELS_] = {0, 1, 5, 21, 85, 341, 1365, 5461, 21845};

    // prep
    {
        int n4 = N_NODES_ * 256 / 4;
        conv_x<<<(n4 + 255) / 256, 256, 0, stream>>>(x, xb, n4);
        int total = 262144 + 262144 + 131072 + 65536 + 65536 + 1024 + 1024 + 512;
        prep_weights<<<(total + 255) / 256, 256, 0, stream>>>(
            W_iou, W_f, Uiou_w, Uf_w, Wk, Wv, Wq, Wl,
            b_iou, b_f, Uiou_b, Uf_b, bk, bv,
            Bt1, Bt2, B3t, Wqt, Wlt, biasX, biasU, bias_kv);
    }

    // upfront x-dependent GEMMs
    launch_gemm(xb + (size_t)21845 * 256, Bt1, biasX, nullptr, xl,
                65536, 768, 256, 1, stream);                       // leaf iou preacts
    launch_gemm(xb, Bt1, biasX, nullptr, xi, 21845, 1024, 256, 1, stream); // internal x preacts
    launch_gemm(xb, Wqt, bq, nullptr, qb, 21845, 256, 256, 1, stream);     // all q

    // leaves
    {
        int total = 65536 * HS;
        cell_leaf<<<(total + 255) / 256, 256, 0, stream>>>(
            xl, h_all + (size_t)21845 * HS, c_all + (size_t)21845 * HS,
            hb + (size_t)21845 * HS, 65536);
    }

    // levels 7,6: dedicated pipeline
    for (int l = 7; l >= 6; l--) {
        int n  = 1 << (2 * l);
        int s0 = starts[l];
        int sc = starts[l + 1];
        int nc = 4 * n;

        launch_gemm(hb + (size_t)sc * 256, B3t, bias_kv, nullptr, KVb,
                    nc, 512, 256, 1, stream);
        int pairs = n * N_HEADS_;
        attn_kernel<<<(pairs * 32 + 255) / 256, 256, 0, stream>>>(
            qb + (size_t)s0 * 256, KVb, outb, n);
        launch_gemm(outb, Wlt, bl, nullptr, hab, n, 256, 256, 1, stream);
        launch_gemm(hab, Bt2, biasU, xi + (size_t)s0 * 1024, ioufb,
                    n, 1024, 256, 1, stream);
        int total = n * HS;
        cell_internal<<<(total + 255) / 256, 256, 0, stream>>>(
            ioufb, c_all + (size_t)sc * HS,
            h_all + (size_t)s0 * HS, c_all + (size_t)s0 * HS,
            hb + (size_t)s0 * HS, n);
    }

    // levels 5..0: fused
    for (int l = 5; l >= 0; l--) {
        int n  = 1 << (2 * l);
        int s0 = starts[l];
        int sc = starts[l + 1];
        int blocks = (n + 7) / 8;
        level_fused<<<blocks, 256, 0, stream>>>(
            hb, c_all, qb, xi, B3t, Wlt, Bt2, bias_kv, bl, biasU,
            h_all, c_all, hb, s0, sc, n);
    }
}